// Round 11
// baseline (211.143 us; speedup 1.0000x reference)
//
#include <hip/hip_runtime.h>

// Transformer block fwd: B=4, T=1024, C=1024, H=16, HS=64.
// MLP1/MLP2: 8-phase 256^2 with B-register-hold (reads 12/4/8/0 per K-tile).
// QKV: 2-phase 128x256 (384 blocks). Wo: 2-phase 64x128. Attn: unpaired+defer-max.

typedef __bf16 bf16_t;
typedef __attribute__((ext_vector_type(8))) __bf16 bfx8;
typedef __attribute__((ext_vector_type(4))) __bf16 bfx4;
typedef __attribute__((ext_vector_type(4))) float f32x4;
typedef __attribute__((ext_vector_type(8))) unsigned short u16x8;
typedef unsigned int u32;

#define MFMA_BF16(a, b, c) __builtin_amdgcn_mfma_f32_16x16x32_bf16((a), (b), (c), 0, 0, 0)
#define GLOAD_LDS16(g, l)                                                     \
  __builtin_amdgcn_global_load_lds((__attribute__((address_space(1))) void*)(g), \
                                   (__attribute__((address_space(3))) void*)(l), 16, 0, 0)
#define SBAR() __builtin_amdgcn_sched_barrier(0)
#define VMW(N)                                          \
  asm volatile("s_waitcnt vmcnt(" #N ")" ::: "memory"); \
  __builtin_amdgcn_sched_barrier(0)

// ---------------- LayerNorm: fp32 in -> bf16 out ----------------
__global__ __launch_bounds__(256) void ln_kernel(const float* __restrict__ x,
                                                 const float* __restrict__ w,
                                                 const float* __restrict__ b,
                                                 bf16_t* __restrict__ out) {
  const int row = blockIdx.x;
  const int tid = threadIdx.x;
  const float4 v = reinterpret_cast<const float4*>(x + (size_t)row * 1024)[tid];
  float s = v.x + v.y + v.z + v.w;
  float s2 = v.x * v.x + v.y * v.y + v.z * v.z + v.w * v.w;
#pragma unroll
  for (int off = 1; off < 64; off <<= 1) {
    s += __shfl_xor(s, off);
    s2 += __shfl_xor(s2, off);
  }
  __shared__ float red[8];
  const int wv = tid >> 6;
  if ((tid & 63) == 0) {
    red[wv] = s;
    red[4 + wv] = s2;
  }
  __syncthreads();
  s = red[0] + red[1] + red[2] + red[3];
  s2 = red[4] + red[5] + red[6] + red[7];
  const float mu = s * (1.0f / 1024.0f);
  const float rs = rsqrtf(s2 * (1.0f / 1024.0f) - mu * mu + 1e-5f);
  const float4 wv4 = reinterpret_cast<const float4*>(w)[tid];
  const float4 bv4 = reinterpret_cast<const float4*>(b)[tid];
  bfx4 o;
  o[0] = (bf16_t)((v.x - mu) * rs * wv4.x + bv4.x);
  o[1] = (bf16_t)((v.y - mu) * rs * wv4.y + bv4.y);
  o[2] = (bf16_t)((v.z - mu) * rs * wv4.z + bv4.z);
  o[3] = (bf16_t)((v.w - mu) * rs * wv4.w + bv4.w);
  reinterpret_cast<bfx4*>(out + (size_t)row * 1024)[tid] = o;
}

// ---------------- Tiled transpose+cast: fp32 [K,N] -> bf16 [N,K] ----------------
__device__ __forceinline__ void tc_body(const float* __restrict__ in,
                                        bf16_t* __restrict__ out, int K, int N, int k0,
                                        int n0, float (*tile)[65], int t) {
  const int rl = t >> 4, cl = (t & 15) * 4;
#pragma unroll
  for (int p = 0; p < 4; ++p) {
    const int r = p * 16 + rl;
    const float4 v = *reinterpret_cast<const float4*>(in + (size_t)(k0 + r) * N + n0 + cl);
    tile[r][cl] = v.x;
    tile[r][cl + 1] = v.y;
    tile[r][cl + 2] = v.z;
    tile[r][cl + 3] = v.w;
  }
  __syncthreads();
#pragma unroll
  for (int p = 0; p < 2; ++p) {
    const int idx = p * 256 + t;
    const int n = idx >> 3, kc = (idx & 7) * 8;
    bfx8 o;
#pragma unroll
    for (int i = 0; i < 8; ++i) o[i] = (bf16_t)tile[kc + i][n];
    *reinterpret_cast<bfx8*>(out + (size_t)(n0 + n) * K + k0 + kc) = o;
  }
}

__global__ __launch_bounds__(256) void transpose_cast(const float* __restrict__ in,
                                                      bf16_t* __restrict__ out, int K,
                                                      int N) {
  __shared__ float tile[64][65];
  tc_body(in, out, K, N, blockIdx.x * 64, blockIdx.y * 64, tile, threadIdx.x);
}

__global__ __launch_bounds__(256) void transpose_qkv(const float* __restrict__ Wq,
                                                     const float* __restrict__ Wk,
                                                     const float* __restrict__ Wv,
                                                     bf16_t* __restrict__ out) {
  __shared__ float tile[64][65];
  const int z = blockIdx.y;  // 0..47
  const int sel = z >> 4, h = z & 15;
  const float* in = ((sel == 0) ? Wq : (sel == 1) ? Wk : Wv) + h * 65536;
  bf16_t* o = out + (size_t)sel * 1048576 + h * 65536;
  tc_body(in, o, 1024, 64, blockIdx.x * 64, 0, tile, threadIdx.x);
}

// ---------------- 2-phase GEMM (QKV / Wo) ----------------
enum { EPI_QKV = 0, EPI_WO = 1 };

template <int EPI, int BM, int BN, int NT>
__global__ __launch_bounds__(NT, 2) void gemm_bt(
    const bf16_t* __restrict__ A, const bf16_t* __restrict__ BT,
    const float* __restrict__ bias, const float* __restrict__ res,
    float* __restrict__ outf, bf16_t* __restrict__ ob0, bf16_t* __restrict__ ob1,
    bf16_t* __restrict__ ob2, int K, int N) {
  constexpr int WM = 2;
  constexpr int WN = NT / 64 / WM;
  constexpr int MF = BM / WM / 16;
  constexpr int NF = BN / WN / 16;
  constexpr int ACH = BM * 64 / (NT * 8);
  constexpr int BCH = BN * 64 / (NT * 8);
  constexpr int LOADS = ACH + BCH;
  static_assert(LOADS == 8 || LOADS == 6, "add a vmcnt case");
  __shared__ __align__(16) bf16_t sA[2][BM * 64];
  __shared__ __align__(16) bf16_t sB[2][BN * 64];
  const int tid = threadIdx.x;
  const int lane = tid & 63;
  const int w = tid >> 6;
  const int wr = w / WN, wc = w % WN;
  const int g = lane >> 4, l15 = lane & 15;
  const int row0 = blockIdx.x * BM, col0 = blockIdx.y * BN;
  const int rowbase = row0 + wr * (BM / WM);
  const int colbase = wc * (BN / WN);

  f32x4 acc[MF][NF] = {};

  auto stage = [&](int k0, int buf) {
#pragma unroll
    for (int j = 0; j < ACH; ++j) {
      const int chunk = j * NT + tid;
      const int r = chunk >> 3, c = chunk & 7;
      GLOAD_LDS16(A + (size_t)(row0 + r) * K + k0 + ((c ^ (r & 7)) * 8),
                  sA[buf] + chunk * 8);
    }
#pragma unroll
    for (int j = 0; j < BCH; ++j) {
      const int chunk = j * NT + tid;
      const int r = chunk >> 3, c = chunk & 7;
      GLOAD_LDS16(BT + (size_t)(col0 + r) * K + k0 + ((c ^ (r & 7)) * 8),
                  sB[buf] + chunk * 8);
    }
  };

  stage(0, 0);
  const int nk = K >> 6;
  for (int t = 0; t < nk; ++t) {
    const int cur = t & 1;
    if (t + 1 < nk) {
      stage((t + 1) << 6, cur ^ 1);
      SBAR();
      if constexpr (LOADS == 8)
        asm volatile("s_waitcnt vmcnt(8)" ::: "memory");
      else
        asm volatile("s_waitcnt vmcnt(6)" ::: "memory");
    } else {
      SBAR();
      asm volatile("s_waitcnt vmcnt(0)" ::: "memory");
    }
    __builtin_amdgcn_s_barrier();
    SBAR();
    const bf16_t* __restrict__ pA = sA[cur];
    const bf16_t* __restrict__ pB = sB[cur];
#pragma unroll
    for (int kk = 0; kk < 2; ++kk) {
      bfx8 af[MF], bfr[NF];
#pragma unroll
      for (int m = 0; m < MF; ++m) {
        const int r = wr * (BM / WM) + m * 16 + l15;
        const int c = (kk * 4 + g) ^ (r & 7);
        af[m] = *reinterpret_cast<const bfx8*>(pA + r * 64 + c * 8);
      }
#pragma unroll
      for (int n = 0; n < NF; ++n) {
        const int r = colbase + n * 16 + l15;
        const int c = (kk * 4 + g) ^ (r & 7);
        bfr[n] = *reinterpret_cast<const bfx8*>(pB + r * 64 + c * 8);
      }
#pragma unroll
      for (int m = 0; m < MF; ++m)
#pragma unroll
        for (int n = 0; n < NF; ++n) acc[m][n] = MFMA_BF16(af[m], bfr[n], acc[m][n]);
    }
    SBAR();
    __builtin_amdgcn_s_barrier();
  }

#pragma unroll
  for (int m = 0; m < MF; ++m) {
#pragma unroll
    for (int n = 0; n < NF; ++n) {
#pragma unroll
      for (int j = 0; j < 4; ++j) {
        const int row = rowbase + m * 16 + (g << 2) + j;
        const int col = col0 + colbase + n * 16 + l15;
        const float v = acc[m][n][j];
        if (EPI == EPI_QKV) {
          const int sel = col >> 10;
          const int h = (col >> 6) & 15, d = col & 63;
          const int bb = row >> 10, t = row & 1023;
          bf16_t* dst = (sel == 0) ? ob0 : (sel == 1) ? ob1 : ob2;
          dst[((size_t)(bb * 16 + h) * 1024 + t) * 64 + d] = (bf16_t)v;
        } else {
          outf[(size_t)row * N + col] = v + bias[col] + res[(size_t)row * N + col];
        }
      }
    }
  }
}

// ---------------- 8-phase 256^2 GEMM (MLP1 / MLP2-splitK) ----------------
// B-register-hold: B-half frags read once per K-tile (ph1:b0, ph2:b1), reused at
// ph3/ph4. Phase reads: 12/4/8/0 ds_read_b128 (was 12/4/12/4).
__device__ __forceinline__ void stageA8(const bf16_t* __restrict__ A, int Ks, int row0,
                                        int k0, int mh, bf16_t* dst, int tid) {
#pragma unroll
  for (int g2 = 0; g2 < 2; ++g2) {
    const int band = g2 * 128 + mh * 64;
    const int row = band + (tid >> 3);
    GLOAD_LDS16(A + (size_t)(row0 + row) * Ks + k0 + (((tid & 7) ^ (row & 7)) * 8),
                dst + band * 64 + tid * 8);
  }
}

__device__ __forceinline__ void stageB8(const bf16_t* __restrict__ BT, int Ks, int col0,
                                        int k0, int nh, bf16_t* dst, int tid) {
#pragma unroll
  for (int g2 = 0; g2 < 2; ++g2) {
    const int rho = g2 * 64 + (tid >> 3);
    const int grow = (rho >> 5) * 64 + nh * 32 + (rho & 31);
    GLOAD_LDS16(BT + (size_t)(col0 + grow) * Ks + k0 + (((tid & 7) ^ (rho & 7)) * 8),
                dst + nh * 8192 + g2 * 4096 + tid * 8);
  }
}

template <int MH>
__device__ __forceinline__ void read_a8(const bf16_t* __restrict__ pA, int wr, int l15,
                                        int g, bfx8 (&af)[4][2]) {
#pragma unroll
  for (int i = 0; i < 4; ++i) {
    const int r = wr * 128 + (MH * 4 + i) * 16 + l15;
#pragma unroll
    for (int kk = 0; kk < 2; ++kk)
      af[i][kk] =
          *reinterpret_cast<const bfx8*>(pA + r * 64 + (((kk * 4 + g) ^ (r & 7)) * 8));
  }
}

template <int NH>
__device__ __forceinline__ void read_b8(const bf16_t* __restrict__ pB, int wc, int l15,
                                        int g, bfx8 (&bf)[2][2]) {
#pragma unroll
  for (int i = 0; i < 2; ++i) {
    const int rho = wc * 32 + i * 16 + l15;
#pragma unroll
    for (int kk = 0; kk < 2; ++kk)
      bf[i][kk] = *reinterpret_cast<const bfx8*>(pB + NH * 8192 + rho * 64 +
                                                 (((kk * 4 + g) ^ (rho & 7)) * 8));
  }
}

template <int MH, int NH>
__device__ __forceinline__ void mma16(const bfx8 (&af)[4][2], const bfx8 (&bf)[2][2],
                                      f32x4 (&acc)[8][4]) {
  __builtin_amdgcn_s_setprio(1);
#pragma unroll
  for (int i = 0; i < 4; ++i)
#pragma unroll
    for (int jn = 0; jn < 2; ++jn)
#pragma unroll
      for (int kk = 0; kk < 2; ++kk)
        acc[MH * 4 + i][NH * 2 + jn] =
            MFMA_BF16(af[i][kk], bf[jn][kk], acc[MH * 4 + i][NH * 2 + jn]);
  __builtin_amdgcn_s_setprio(0);
}

// Phase: ds_reads + stage-issue BEFORE barrier; lgkm0 gate; setprio MFMA; barrier.
#define PHX(READS, STAGE, WAITC, MMA)                   \
  {                                                     \
    READS;                                              \
    STAGE;                                              \
    WAITC;                                              \
    __builtin_amdgcn_s_barrier();                       \
    asm volatile("s_waitcnt lgkmcnt(0)" ::: "memory");  \
    SBAR();                                             \
    MMA;                                                \
    SBAR();                                             \
    __builtin_amdgcn_s_barrier();                       \
  }

template <bool PRELU>
__global__ __launch_bounds__(512, 1) void gemm_8ph(
    const bf16_t* __restrict__ A, const bf16_t* __restrict__ BT,
    const float* __restrict__ bias, const float* __restrict__ prelu,
    bf16_t* __restrict__ outb, int Ks, int Klen, int N, size_t zstride) {
  __shared__ __align__(16) bf16_t sA[2][256 * 64];
  __shared__ __align__(16) bf16_t sB[2][256 * 64];
  const int tid = threadIdx.x;
  const int lane = tid & 63;
  const int w = tid >> 6;
  const int wr = w >> 2, wc = w & 3;  // 2M x 4N
  const int g = lane >> 4, l15 = lane & 15;
  const int row0 = blockIdx.x * 256, col0 = blockIdx.y * 256;
  const int koff = blockIdx.z * Klen;

  f32x4 acc[8][4] = {};
  bfx8 af[4][2];
  bfx8 b0[2][2], b1[2][2];  // B-half fragments, held across MH phases

  // prologue: tile0 (4 halves in consume order), tile1 first 2 halves
  stageA8(A, Ks, row0, koff, 0, sA[0], tid);       // A0h0
  stageB8(BT, Ks, col0, koff, 0, sB[0], tid);      // B0h0
  stageB8(BT, Ks, col0, koff, 1, sB[0], tid);      // B0h1
  stageA8(A, Ks, row0, koff, 1, sA[0], tid);       // A0h1
  stageA8(A, Ks, row0, koff + 64, 0, sA[1], tid);  // A1h0
  stageB8(BT, Ks, col0, koff + 64, 0, sB[1], tid); // B1h0
  VMW(4);  // tile0 landed; A1h0/B1h0 in flight
  __builtin_amdgcn_s_barrier();

  const int nt = Klen >> 7;
  for (int j = 0; j < nt; ++j) {
    const bool more = (j + 1 < nt);
    const int ku1 = koff + ((2 * j + 1) << 6);
    const int k2 = koff + ((2 * j + 2) << 6);
    const int k3 = koff + ((2 * j + 3) << 6);
    // tile u0 (sA[0], sB[0])
    PHX((read_a8<0>(sA[0], wr, l15, g, af), read_b8<0>(sB[0], wc, l15, g, b0)),
        stageB8(BT, Ks, col0, ku1, 1, sB[1], tid), ,
        (mma16<0, 0>(af, b0, acc)));
    PHX((read_b8<1>(sB[0], wc, l15, g, b1)),
        stageA8(A, Ks, row0, ku1, 1, sA[1], tid), ,
        (mma16<0, 1>(af, b1, acc)));
    PHX((read_a8<1>(sA[0], wr, l15, g, af)),
        if (more) stageA8(A, Ks, row0, k2, 0, sA[0], tid), ,
        (mma16<1, 0>(af, b0, acc)));
    PHX(, if (more) stageB8(BT, Ks, col0, k2, 0, sB[0], tid),
        if (more) { VMW(4); } else { VMW(0); },
        (mma16<1, 1>(af, b1, acc)));
    // tile u1 (sA[1], sB[1])
    PHX((read_a8<0>(sA[1], wr, l15, g, af), read_b8<0>(sB[1], wc, l15, g, b0)),
        if (more) stageB8(BT, Ks, col0, k2, 1, sB[0], tid), ,
        (mma16<0, 0>(af, b0, acc)));
    PHX((read_b8<1>(sB[1], wc, l15, g, b1)),
        if (more) stageA8(A, Ks, row0, k2, 1, sA[0], tid), ,
        (mma16<0, 1>(af, b1, acc)));
    PHX((read_a8<1>(sA[1], wr, l15, g, af)),
        if (more) stageA8(A, Ks, row0, k3, 0, sA[1], tid), ,
        (mma16<1, 0>(af, b0, acc)));
    PHX(, if (more) stageB8(BT, Ks, col0, k3, 0, sB[1], tid),
        if (more) { VMW(4); },
        (mma16<1, 1>(af, b1, acc)));
  }

  bf16_t* o = outb + (size_t)blockIdx.z * zstride;
  const float pa = PRELU ? prelu[0] : 0.0f;
#pragma unroll
  for (int m = 0; m < 8; ++m) {
#pragma unroll
    for (int n = 0; n < 4; ++n) {
#pragma unroll
      for (int j = 0; j < 4; ++j) {
        const int row = row0 + wr * 128 + m * 16 + (g << 2) + j;
        const int col = col0 + wc * 64 + n * 16 + l15;
        float t = acc[m][n][j];
        if (PRELU) {
          t += bias[col];
          t = (t > 0.0f) ? t : pa * t;
        }
        o[(size_t)row * N + col] = (bf16_t)t;
      }
    }
  }
}

// ---------------- MLP2 split-K reduce: out += b2 + sum(partials) ----------------
__global__ __launch_bounds__(256) void reduce_mlp2(const bf16_t* __restrict__ part,
                                                   const float* __restrict__ b2,
                                                   float* __restrict__ out) {
  const int idx = (blockIdx.x * 256 + threadIdx.x) * 8;
  const int col = idx & 1023;
  float a[8];
  {
    const float4 o0 = *reinterpret_cast<const float4*>(out + idx);
    const float4 o1 = *reinterpret_cast<const float4*>(out + idx + 4);
    const float4 b0 = *reinterpret_cast<const float4*>(b2 + col);
    const float4 b1 = *reinterpret_cast<const float4*>(b2 + col + 4);
    a[0] = o0.x + b0.x; a[1] = o0.y + b0.y; a[2] = o0.z + b0.z; a[3] = o0.w + b0.w;
    a[4] = o1.x + b1.x; a[5] = o1.y + b1.y; a[6] = o1.z + b1.z; a[7] = o1.w + b1.w;
  }
#pragma unroll
  for (int s = 0; s < 4; ++s) {
    const u16x8 p = *reinterpret_cast<const u16x8*>(part + (size_t)s * 4194304 + idx);
#pragma unroll
    for (int i = 0; i < 8; ++i) a[i] += __uint_as_float((u32)p[i] << 16);
  }
  float4 r0{a[0], a[1], a[2], a[3]}, r1{a[4], a[5], a[6], a[7]};
  *reinterpret_cast<float4*>(out + idx) = r0;
  *reinterpret_cast<float4*>(out + idx + 4) = r1;
}

// ---------------- Causal flash attention ----------------
__global__ __launch_bounds__(256) void attn_kernel(const bf16_t* __restrict__ kproj,
                                                   const bf16_t* __restrict__ qproj,
                                                   const bf16_t* __restrict__ vproj,
                                                   bf16_t* __restrict__ att) {
  __shared__ __align__(16) bf16_t sK[2][64 * 64];
  __shared__ __align__(16) bf16_t sVt[2][64 * 64];
  __shared__ __align__(16) bf16_t sP[4][16 * 64];
  const int tid = threadIdx.x, lane = tid & 63, w = tid >> 6;
  const int g = lane >> 4, l15 = lane & 15;
  const int f = blockIdx.x;
  const int tb = 15 - ((f >> 3) >> 3);
  const int bh = (((f >> 3) & 7) << 3) + (f & 7);
  const size_t head = (size_t)bh * (1024 * 64);
  const int b = bh >> 4, h = bh & 15;
  const int vrow = 2 * (tid >> 3);
  const int vdb = tid & 7;
  const int t0 = tb * 64;
  const int nsb = tb + 1;

  bfx8 aq0, aq1;
  {
    const bf16_t* qrow = kproj + head + (size_t)(t0 + w * 16 + l15) * 64 + g * 8;
    aq0 = *reinterpret_cast<const bfx8*>(qrow);
    aq1 = *reinterpret_cast<const bfx8*>(qrow + 32);
  }

  {
#pragma unroll
    for (int j = 0; j < 2; ++j) {
      const int chunk = j * 256 + tid;
      const int r = chunk >> 3, c = chunk & 7;
      const int cs = c ^ (r & 7);
      GLOAD_LDS16(qproj + head + (size_t)r * 64 + cs * 8, sK[0] + chunk * 8);
    }
    const bf16_t* vp = vproj + head + (size_t)vrow * 64 + vdb * 8;
    const u16x8 v0 = *reinterpret_cast<const u16x8*>(vp);
    const u16x8 v1 = *reinterpret_cast<const u16x8*>(vp + 64);
#pragma unroll
    for (int i = 0; i < 8; ++i) {
      const int d = vdb * 8 + i;
      const int cc = ((vrow >> 3) ^ i ^ vdb) & 7;
      const u32 pk = ((u32)v1[i] << 16) | (u32)v0[i];
      *reinterpret_cast<u32*>(sVt[0] + d * 64 + cc * 8 + (vrow & 7)) = pk;
    }
  }
  __syncthreads();

  f32x4 accO[4] = {};
  float m2[4], lp[4];
#pragma unroll
  for (int j = 0; j < 4; ++j) {
    m2[j] = -1e30f;
    lp[j] = 0.0f;
  }

  for (int sb = 0; sb < nsb; ++sb) {
    const int cur = sb & 1;
    const bool pf = (sb + 1 < nsb);
    const bool diag = (sb == tb);
    u16x8 v0n, v1n;
    if (pf) {
      const int s0n = (sb + 1) * 64;
#pragma unroll
      for (int j = 0; j < 2; ++j) {
        const int chunk = j * 256 + tid;
        const int r = chunk >> 3, c = chunk & 7;
        const int cs = c ^ (r & 7);
        GLOAD_LDS16(qproj + head + (size_t)(s0n + r) * 64 + cs * 8, sK[cur ^ 1] + chunk * 8);
      }
      const bf16_t* vp = vproj + head + (size_t)(s0n + vrow) * 64 + vdb * 8;
      v0n = *reinterpret_cast<const u16x8*>(vp);
      v1n = *reinterpret_cast<const u16x8*>(vp + 64);
    }

    f32x4 accS[4] = {};
    const bf16_t* sKc = sK[cur];
#pragma unroll
    for (int kk = 0; kk < 2; ++kk) {
      const bfx8 aq = kk ? aq1 : aq0;
#pragma unroll
      for (int n = 0; n < 4; ++n) {
        const int r = n * 16 + l15;
        const int c = (kk * 4 + g) ^ (r & 7);
        const bfx8 bk = *reinterpret_cast<const bfx8*>(sKc + r * 64 + c * 8);
        accS[n] = MFMA_BF16(aq, bk, accS[n]);
      }
    }

    constexpr float SC = 0.04508056640625f;  // log2(e)/32
    const int rbase = t0 + w * 16 + (g << 2);
    const int cbase = sb * 64 + l15;
    float rmx[4];
    float dmax = -3e38f;
#pragma unroll
    for (int j = 0; j < 4; ++j) {
      const int t = rbase + j;
      float mx = -1e30f;
      if (diag) {
#pragma unroll
        for (int n = 0; n < 4; ++n) {
          float v = accS[n][j] * SC;
          v = ((cbase + n * 16) <= t) ? v : -1e30f;
          accS[n][j] = v;
          mx = fmaxf(mx, v);
        }
      } else {
#pragma unroll
        for (int n = 0; n < 4; ++n) {
          const float v = accS[n][j] * SC;
          accS[n][j] = v;
          mx = fmaxf(mx, v);
        }
      }
      rmx[j] = mx;
      dmax = fmaxf(dmax, mx - m2[j]);
    }
    if (__any(dmax > 8.0f)) {
#pragma unroll
      for (int j = 0; j < 4; ++j) {
        float mx = rmx[j];
        mx = fmaxf(mx, __shfl_xor(mx, 1));
        mx = fmaxf(mx, __shfl_xor(mx, 2));
        mx = fmaxf(mx, __shfl_xor(mx, 4));
        mx = fmaxf(mx, __shfl_xor(mx, 8));
        const float mnew = fmaxf(m2[j], mx);
        const float al = __builtin_amdgcn_exp2f(m2[j] - mnew);
        m2[j] = mnew;
        lp[j] *= al;
#pragma unroll
        for (int n = 0; n < 4; ++n) accO[n][j] *= al;
      }
    }
#pragma unroll
    for (int j = 0; j < 4; ++j) {
      float s = 0.0f;
#pragma unroll
      for (int n = 0; n < 4; ++n) {
        const float p = __builtin_amdgcn_exp2f(accS[n][j] - m2[j]);
        accS[n][j] = p;
        s += p;
      }
      lp[j] += s;
    }

    bf16_t* sPw = sP[w];
#pragma unroll
    for (int n = 0; n < 4; ++n)
#pragma unroll
      for (int j = 0; j < 4; ++j) {
        const int r = (g << 2) + j;
        const int s = n * 16 + l15;
        const int cc = (s >> 3) ^ (r & 7);
        sPw[r * 64 + cc * 8 + (s & 7)] = (bf16_t)accS[n][j];
      }

    const bf16_t* sVc = sVt[cur];
#pragma unroll
    for (int kk = 0; kk < 2; ++kk) {
      bfx8 ap;
      {
        const int r = l15;
        const int c = (kk * 4 + g) ^ (r & 7);
        ap = *reinterpret_cast<const bfx8*>(sPw + r * 64 + c * 8);
      }
#pragma unroll
      for (int n = 0; n < 4; ++n) {
        const int d = n * 16 + l15;
        const int c = (kk * 4 + g) ^ (d & 7) ^ ((d >> 3) & 7);
        const bfx8 bv = *reinterpret_cast<const bfx8*>(sVc + d * 64 + c * 8);
        accO[n] = MFMA_BF16(ap, bv, accO[n]);
      }
    }

    if (pf) {
#pragma unroll
      for (int i = 0; i < 8; ++i) {
        const int d = vdb * 8 + i;
        const int cc = ((vrow >> 3) ^ i ^ vdb) & 7;
        const u32 pk = ((u32)v1n[i] << 16) | (u32)v0n[i];
        *reinterpret_cast<u32*>(sVt[cur ^ 1] + d * 64 + cc * 8 + (vrow & 7)) = pk;
      }
    }
    __syncthreads();
  }

#pragma unroll
  for (int j = 0; j < 4; ++j) {
    float l = lp[j];
    l += __shfl_xor(l, 1);
    l += __shfl_xor(l, 2);
    l += __shfl_xor(l, 4);
    l += __shfl_xor(l, 8);
    const float inv = 1.0f / l;
    const int t = t0 + w * 16 + (g << 2) + j;
#pragma unroll
    for (int n = 0; n < 4; ++n) {
      const int d = n * 16 + l15;
      att[((size_t)(b * 1024 + t)) * 1024 + h * 64 + d] = (bf16_t)(accO[n][j] * inv);
    }
  }
}

extern "C" void kernel_launch(void* const* d_in, const int* in_sizes, int n_in,
                              void* d_out, int out_size, void* d_ws, size_t ws_size,
                              hipStream_t stream) {
  (void)in_sizes; (void)n_in; (void)out_size; (void)ws_size;
  const float* x = (const float*)d_in[0];
  const float* ln1w = (const float*)d_in[1];
  const float* ln1b = (const float*)d_in[2];
  const float* Wk = (const float*)d_in[3];
  const float* Wq = (const float*)d_in[4];
  const float* Wv = (const float*)d_in[5];
  const float* Wo = (const float*)d_in[6];
  const float* bo = (const float*)d_in[7];
  const float* ln2w = (const float*)d_in[8];
  const float* ln2b = (const float*)d_in[9];
  const float* W1 = (const float*)d_in[10];
  const float* b1 = (const float*)d_in[11];
  const float* pa = (const float*)d_in[12];
  const float* W2 = (const float*)d_in[13];
  const float* b2 = (const float*)d_in[14];
  float* out = (float*)d_out;
  char* ws = (char*)d_ws;
  const size_t MB = 1ull << 20;
  bf16_t* h1 = (bf16_t*)(ws + 0 * MB);      // [4096,1024]
  bf16_t* h2 = (bf16_t*)(ws + 8 * MB);      // [4096,1024]
  bf16_t* qb = (bf16_t*)(ws + 16 * MB);     // [B*H,1024,64]
  bf16_t* kb = (bf16_t*)(ws + 24 * MB);
  bf16_t* vb = (bf16_t*)(ws + 32 * MB);
  bf16_t* attb = (bf16_t*)(ws + 40 * MB);   // [4096,1024]
  bf16_t* fbuf = (bf16_t*)(ws + 48 * MB);   // [4096,4096]
  bf16_t* part = (bf16_t*)(ws + 16 * MB);   // MLP2 partials [4][4096,1024]
  bf16_t* WqkvT = (bf16_t*)(ws + 80 * MB);  // [3072,1024]
  bf16_t* WoT = (bf16_t*)(ws + 86 * MB);    // [1024,1024]
  bf16_t* W1T = (bf16_t*)(ws + 88 * MB);    // [4096,1024]
  bf16_t* W2T = (bf16_t*)(ws + 96 * MB);    // [1024,4096]

  transpose_qkv<<<dim3(16, 48), 256, 0, stream>>>(Wq, Wk, Wv, WqkvT);
  transpose_cast<<<dim3(16, 16), 256, 0, stream>>>(Wo, WoT, 1024, 1024);
  transpose_cast<<<dim3(16, 64), 256, 0, stream>>>(W1, W1T, 1024, 4096);
  transpose_cast<<<dim3(64, 16), 256, 0, stream>>>(W2, W2T, 4096, 1024);

  ln_kernel<<<4096, 256, 0, stream>>>(x, ln1w, ln1b, h1);
  gemm_bt<EPI_QKV, 128, 256, 512><<<dim3(32, 12), 512, 0, stream>>>(
      h1, WqkvT, nullptr, nullptr, nullptr, qb, kb, vb, 1024, 3072);
  attn_kernel<<<1024, 256, 0, stream>>>(kb, qb, vb, attb);
  gemm_bt<EPI_WO, 64, 128, 256><<<dim3(64, 8), 256, 0, stream>>>(
      attb, WoT, bo, x, out, nullptr, nullptr, nullptr, 1024, 1024);
  ln_kernel<<<4096, 256, 0, stream>>>(out, ln2w, ln2b, h2);
  gemm_8ph<true><<<dim3(16, 16, 1), 512, 0, stream>>>(h2, W1T, b1, pa, fbuf, 1024, 1024,
                                                      4096, 0);
  gemm_8ph<false><<<dim3(16, 4, 4), 512, 0, stream>>>(fbuf, W2T, nullptr, nullptr, part,
                                                      4096, 1024, 1024, 4194304);
  reduce_mlp2<<<2048, 256, 0, stream>>>(part, b2, out);
}

// Round 12
// 203.438 us; speedup vs baseline: 1.0379x; 1.0379x over previous
//
#include <hip/hip_runtime.h>

// Transformer block fwd: B=4, T=1024, C=1024, H=16, HS=64.
// MLP1/MLP2: 8-phase 256^2 + XCD swizzle. QKV: 2ph 256^2 + swizzle. Wo: 2ph 64x128.
// Attn: unpaired/XCD-swizzled/defer-max.

typedef __bf16 bf16_t;
typedef __attribute__((ext_vector_type(8))) __bf16 bfx8;
typedef __attribute__((ext_vector_type(4))) __bf16 bfx4;
typedef __attribute__((ext_vector_type(4))) float f32x4;
typedef __attribute__((ext_vector_type(8))) unsigned short u16x8;
typedef unsigned int u32;

#define MFMA_BF16(a, b, c) __builtin_amdgcn_mfma_f32_16x16x32_bf16((a), (b), (c), 0, 0, 0)
#define GLOAD_LDS16(g, l)                                                     \
  __builtin_amdgcn_global_load_lds((__attribute__((address_space(1))) void*)(g), \
                                   (__attribute__((address_space(3))) void*)(l), 16, 0, 0)
#define SBAR() __builtin_amdgcn_sched_barrier(0)
#define VMW(N)                                          \
  asm volatile("s_waitcnt vmcnt(" #N ")" ::: "memory"); \
  __builtin_amdgcn_sched_barrier(0)

// bijective XCD chunked remap (requires nb % 8 == 0)
__device__ __forceinline__ int xcd_swz(int wg, int nb) {
  return (wg & 7) * (nb >> 3) + (wg >> 3);
}

// ---------------- LayerNorm: fp32 in -> bf16 out ----------------
__global__ __launch_bounds__(256) void ln_kernel(const float* __restrict__ x,
                                                 const float* __restrict__ w,
                                                 const float* __restrict__ b,
                                                 bf16_t* __restrict__ out) {
  const int row = blockIdx.x;
  const int tid = threadIdx.x;
  const float4 v = reinterpret_cast<const float4*>(x + (size_t)row * 1024)[tid];
  float s = v.x + v.y + v.z + v.w;
  float s2 = v.x * v.x + v.y * v.y + v.z * v.z + v.w * v.w;
#pragma unroll
  for (int off = 1; off < 64; off <<= 1) {
    s += __shfl_xor(s, off);
    s2 += __shfl_xor(s2, off);
  }
  __shared__ float red[8];
  const int wv = tid >> 6;
  if ((tid & 63) == 0) {
    red[wv] = s;
    red[4 + wv] = s2;
  }
  __syncthreads();
  s = red[0] + red[1] + red[2] + red[3];
  s2 = red[4] + red[5] + red[6] + red[7];
  const float mu = s * (1.0f / 1024.0f);
  const float rs = rsqrtf(s2 * (1.0f / 1024.0f) - mu * mu + 1e-5f);
  const float4 wv4 = reinterpret_cast<const float4*>(w)[tid];
  const float4 bv4 = reinterpret_cast<const float4*>(b)[tid];
  bfx4 o;
  o[0] = (bf16_t)((v.x - mu) * rs * wv4.x + bv4.x);
  o[1] = (bf16_t)((v.y - mu) * rs * wv4.y + bv4.y);
  o[2] = (bf16_t)((v.z - mu) * rs * wv4.z + bv4.z);
  o[3] = (bf16_t)((v.w - mu) * rs * wv4.w + bv4.w);
  reinterpret_cast<bfx4*>(out + (size_t)row * 1024)[tid] = o;
}

// ---------------- Tiled transpose+cast: fp32 [K,N] -> bf16 [N,K] ----------------
__device__ __forceinline__ void tc_body(const float* __restrict__ in,
                                        bf16_t* __restrict__ out, int K, int N, int k0,
                                        int n0, float (*tile)[65], int t) {
  const int rl = t >> 4, cl = (t & 15) * 4;
#pragma unroll
  for (int p = 0; p < 4; ++p) {
    const int r = p * 16 + rl;
    const float4 v = *reinterpret_cast<const float4*>(in + (size_t)(k0 + r) * N + n0 + cl);
    tile[r][cl] = v.x;
    tile[r][cl + 1] = v.y;
    tile[r][cl + 2] = v.z;
    tile[r][cl + 3] = v.w;
  }
  __syncthreads();
#pragma unroll
  for (int p = 0; p < 2; ++p) {
    const int idx = p * 256 + t;
    const int n = idx >> 3, kc = (idx & 7) * 8;
    bfx8 o;
#pragma unroll
    for (int i = 0; i < 8; ++i) o[i] = (bf16_t)tile[kc + i][n];
    *reinterpret_cast<bfx8*>(out + (size_t)(n0 + n) * K + k0 + kc) = o;
  }
}

__global__ __launch_bounds__(256) void transpose_cast(const float* __restrict__ in,
                                                      bf16_t* __restrict__ out, int K,
                                                      int N) {
  __shared__ float tile[64][65];
  tc_body(in, out, K, N, blockIdx.x * 64, blockIdx.y * 64, tile, threadIdx.x);
}

__global__ __launch_bounds__(256) void transpose_qkv(const float* __restrict__ Wq,
                                                     const float* __restrict__ Wk,
                                                     const float* __restrict__ Wv,
                                                     bf16_t* __restrict__ out) {
  __shared__ float tile[64][65];
  const int z = blockIdx.y;  // 0..47
  const int sel = z >> 4, h = z & 15;
  const float* in = ((sel == 0) ? Wq : (sel == 1) ? Wk : Wv) + h * 65536;
  bf16_t* o = out + (size_t)sel * 1048576 + h * 65536;
  tc_body(in, o, 1024, 64, blockIdx.x * 64, 0, tile, threadIdx.x);
}

// ---------------- 2-phase GEMM (QKV / Wo), XCD-swizzled ----------------
enum { EPI_QKV = 0, EPI_WO = 1 };

template <int EPI, int BM, int BN, int NT>
__global__ __launch_bounds__(NT, 2) void gemm_bt(
    const bf16_t* __restrict__ A, const bf16_t* __restrict__ BT,
    const float* __restrict__ bias, const float* __restrict__ res,
    float* __restrict__ outf, bf16_t* __restrict__ ob0, bf16_t* __restrict__ ob1,
    bf16_t* __restrict__ ob2, int K, int N) {
  constexpr int WM = 2;
  constexpr int WN = NT / 64 / WM;
  constexpr int MF = BM / WM / 16;
  constexpr int NF = BN / WN / 16;
  constexpr int ACH = BM * 64 / (NT * 8);
  constexpr int BCH = BN * 64 / (NT * 8);
  constexpr int LOADS = ACH + BCH;
  static_assert(LOADS == 8 || LOADS == 6, "add a vmcnt case");
  __shared__ __align__(16) bf16_t sA[2][BM * 64];
  __shared__ __align__(16) bf16_t sB[2][BN * 64];
  const int tid = threadIdx.x;
  const int lane = tid & 63;
  const int w = tid >> 6;
  const int wr = w / WN, wc = w % WN;
  const int g = lane >> 4, l15 = lane & 15;
  const int nb = gridDim.x * gridDim.y;
  const int wg = blockIdx.y * gridDim.x + blockIdx.x;
  const int sg = xcd_swz(wg, nb);
  const int bx = sg % gridDim.x, by = sg / gridDim.x;
  const int row0 = bx * BM, col0 = by * BN;
  const int rowbase = row0 + wr * (BM / WM);
  const int colbase = wc * (BN / WN);

  f32x4 acc[MF][NF] = {};

  auto stage = [&](int k0, int buf) {
#pragma unroll
    for (int j = 0; j < ACH; ++j) {
      const int chunk = j * NT + tid;
      const int r = chunk >> 3, c = chunk & 7;
      GLOAD_LDS16(A + (size_t)(row0 + r) * K + k0 + ((c ^ (r & 7)) * 8),
                  sA[buf] + chunk * 8);
    }
#pragma unroll
    for (int j = 0; j < BCH; ++j) {
      const int chunk = j * NT + tid;
      const int r = chunk >> 3, c = chunk & 7;
      GLOAD_LDS16(BT + (size_t)(col0 + r) * K + k0 + ((c ^ (r & 7)) * 8),
                  sB[buf] + chunk * 8);
    }
  };

  stage(0, 0);
  const int nk = K >> 6;
  for (int t = 0; t < nk; ++t) {
    const int cur = t & 1;
    if (t + 1 < nk) {
      stage((t + 1) << 6, cur ^ 1);
      SBAR();
      if constexpr (LOADS == 8)
        asm volatile("s_waitcnt vmcnt(8)" ::: "memory");
      else
        asm volatile("s_waitcnt vmcnt(6)" ::: "memory");
    } else {
      SBAR();
      asm volatile("s_waitcnt vmcnt(0)" ::: "memory");
    }
    __builtin_amdgcn_s_barrier();
    SBAR();
    const bf16_t* __restrict__ pA = sA[cur];
    const bf16_t* __restrict__ pB = sB[cur];
#pragma unroll
    for (int kk = 0; kk < 2; ++kk) {
      bfx8 af[MF], bfr[NF];
#pragma unroll
      for (int m = 0; m < MF; ++m) {
        const int r = wr * (BM / WM) + m * 16 + l15;
        const int c = (kk * 4 + g) ^ (r & 7);
        af[m] = *reinterpret_cast<const bfx8*>(pA + r * 64 + c * 8);
      }
#pragma unroll
      for (int n = 0; n < NF; ++n) {
        const int r = colbase + n * 16 + l15;
        const int c = (kk * 4 + g) ^ (r & 7);
        bfr[n] = *reinterpret_cast<const bfx8*>(pB + r * 64 + c * 8);
      }
#pragma unroll
      for (int m = 0; m < MF; ++m)
#pragma unroll
        for (int n = 0; n < NF; ++n) acc[m][n] = MFMA_BF16(af[m], bfr[n], acc[m][n]);
    }
    SBAR();
    __builtin_amdgcn_s_barrier();
  }

#pragma unroll
  for (int m = 0; m < MF; ++m) {
#pragma unroll
    for (int n = 0; n < NF; ++n) {
#pragma unroll
      for (int j = 0; j < 4; ++j) {
        const int row = rowbase + m * 16 + (g << 2) + j;
        const int col = col0 + colbase + n * 16 + l15;
        const float v = acc[m][n][j];
        if (EPI == EPI_QKV) {
          const int sel = col >> 10;
          const int h = (col >> 6) & 15, d = col & 63;
          const int bb = row >> 10, t = row & 1023;
          bf16_t* dst = (sel == 0) ? ob0 : (sel == 1) ? ob1 : ob2;
          dst[((size_t)(bb * 16 + h) * 1024 + t) * 64 + d] = (bf16_t)v;
        } else {
          outf[(size_t)row * N + col] = v + bias[col] + res[(size_t)row * N + col];
        }
      }
    }
  }
}

// ---------------- 8-phase 256^2 GEMM (MLP1 / MLP2-splitK), XCD-swizzled --------
__device__ __forceinline__ void stageA8(const bf16_t* __restrict__ A, int Ks, int row0,
                                        int k0, int mh, bf16_t* dst, int tid) {
#pragma unroll
  for (int g2 = 0; g2 < 2; ++g2) {
    const int band = g2 * 128 + mh * 64;
    const int row = band + (tid >> 3);
    GLOAD_LDS16(A + (size_t)(row0 + row) * Ks + k0 + (((tid & 7) ^ (row & 7)) * 8),
                dst + band * 64 + tid * 8);
  }
}

__device__ __forceinline__ void stageB8(const bf16_t* __restrict__ BT, int Ks, int col0,
                                        int k0, int nh, bf16_t* dst, int tid) {
#pragma unroll
  for (int g2 = 0; g2 < 2; ++g2) {
    const int rho = g2 * 64 + (tid >> 3);
    const int grow = (rho >> 5) * 64 + nh * 32 + (rho & 31);
    GLOAD_LDS16(BT + (size_t)(col0 + grow) * Ks + k0 + (((tid & 7) ^ (rho & 7)) * 8),
                dst + nh * 8192 + g2 * 4096 + tid * 8);
  }
}

template <int MH>
__device__ __forceinline__ void read_a8(const bf16_t* __restrict__ pA, int wr, int l15,
                                        int g, bfx8 (&af)[4][2]) {
#pragma unroll
  for (int i = 0; i < 4; ++i) {
    const int r = wr * 128 + (MH * 4 + i) * 16 + l15;
#pragma unroll
    for (int kk = 0; kk < 2; ++kk)
      af[i][kk] =
          *reinterpret_cast<const bfx8*>(pA + r * 64 + (((kk * 4 + g) ^ (r & 7)) * 8));
  }
}

template <int NH>
__device__ __forceinline__ void read_b8(const bf16_t* __restrict__ pB, int wc, int l15,
                                        int g, bfx8 (&bf)[2][2]) {
#pragma unroll
  for (int i = 0; i < 2; ++i) {
    const int rho = wc * 32 + i * 16 + l15;
#pragma unroll
    for (int kk = 0; kk < 2; ++kk)
      bf[i][kk] = *reinterpret_cast<const bfx8*>(pB + NH * 8192 + rho * 64 +
                                                 (((kk * 4 + g) ^ (rho & 7)) * 8));
  }
}

template <int MH, int NH>
__device__ __forceinline__ void mma16(const bfx8 (&af)[4][2], const bfx8 (&bf)[2][2],
                                      f32x4 (&acc)[8][4]) {
  __builtin_amdgcn_s_setprio(1);
#pragma unroll
  for (int i = 0; i < 4; ++i)
#pragma unroll
    for (int jn = 0; jn < 2; ++jn)
#pragma unroll
      for (int kk = 0; kk < 2; ++kk)
        acc[MH * 4 + i][NH * 2 + jn] =
            MFMA_BF16(af[i][kk], bf[jn][kk], acc[MH * 4 + i][NH * 2 + jn]);
  __builtin_amdgcn_s_setprio(0);
}

#define PHX(READS, STAGE, WAITC, MMA)                   \
  {                                                     \
    READS;                                              \
    STAGE;                                              \
    WAITC;                                              \
    __builtin_amdgcn_s_barrier();                       \
    asm volatile("s_waitcnt lgkmcnt(0)" ::: "memory");  \
    SBAR();                                             \
    MMA;                                                \
    SBAR();                                             \
    __builtin_amdgcn_s_barrier();                       \
  }

template <bool PRELU>
__global__ __launch_bounds__(512, 1) void gemm_8ph(
    const bf16_t* __restrict__ A, const bf16_t* __restrict__ BT,
    const float* __restrict__ bias, const float* __restrict__ prelu,
    bf16_t* __restrict__ outb, int Ks, int Klen, int N, size_t zstride, int nx,
    int nxy) {
  __shared__ __align__(16) bf16_t sA[2][256 * 64];
  __shared__ __align__(16) bf16_t sB[2][256 * 64];
  const int tid = threadIdx.x;
  const int lane = tid & 63;
  const int w = tid >> 6;
  const int wr = w >> 2, wc = w & 3;  // 2M x 4N
  const int g = lane >> 4, l15 = lane & 15;
  const int sg = xcd_swz(blockIdx.x, gridDim.x);
  const int bz = sg / nxy;
  const int rxy = sg - bz * nxy;
  const int by = rxy / nx, bx = rxy - by * nx;
  const int row0 = bx * 256, col0 = by * 256;
  const int koff = bz * Klen;

  f32x4 acc[8][4] = {};
  bfx8 af[4][2];
  bfx8 b0[2][2], b1[2][2];  // B-half fragments, held across MH phases

  stageA8(A, Ks, row0, koff, 0, sA[0], tid);       // A0h0
  stageB8(BT, Ks, col0, koff, 0, sB[0], tid);      // B0h0
  stageB8(BT, Ks, col0, koff, 1, sB[0], tid);      // B0h1
  stageA8(A, Ks, row0, koff, 1, sA[0], tid);       // A0h1
  stageA8(A, Ks, row0, koff + 64, 0, sA[1], tid);  // A1h0
  stageB8(BT, Ks, col0, koff + 64, 0, sB[1], tid); // B1h0
  VMW(4);
  __builtin_amdgcn_s_barrier();

  const int nt = Klen >> 7;
  for (int j = 0; j < nt; ++j) {
    const bool more = (j + 1 < nt);
    const int ku1 = koff + ((2 * j + 1) << 6);
    const int k2 = koff + ((2 * j + 2) << 6);
    const int k3 = koff + ((2 * j + 3) << 6);
    // tile u0 (sA[0], sB[0])
    PHX((read_a8<0>(sA[0], wr, l15, g, af), read_b8<0>(sB[0], wc, l15, g, b0)),
        stageB8(BT, Ks, col0, ku1, 1, sB[1], tid), ,
        (mma16<0, 0>(af, b0, acc)));
    PHX((read_b8<1>(sB[0], wc, l15, g, b1)),
        stageA8(A, Ks, row0, ku1, 1, sA[1], tid), ,
        (mma16<0, 1>(af, b1, acc)));
    PHX((read_a8<1>(sA[0], wr, l15, g, af)),
        if (more) stageA8(A, Ks, row0, k2, 0, sA[0], tid), ,
        (mma16<1, 0>(af, b0, acc)));
    PHX(, if (more) stageB8(BT, Ks, col0, k2, 0, sB[0], tid),
        if (more) { VMW(4); } else { VMW(0); },
        (mma16<1, 1>(af, b1, acc)));
    // tile u1 (sA[1], sB[1])
    PHX((read_a8<0>(sA[1], wr, l15, g, af), read_b8<0>(sB[1], wc, l15, g, b0)),
        if (more) stageB8(BT, Ks, col0, k2, 1, sB[0], tid), ,
        (mma16<0, 0>(af, b0, acc)));
    PHX((read_b8<1>(sB[1], wc, l15, g, b1)),
        if (more) stageA8(A, Ks, row0, k2, 1, sA[0], tid), ,
        (mma16<0, 1>(af, b1, acc)));
    PHX((read_a8<1>(sA[1], wr, l15, g, af)),
        if (more) stageA8(A, Ks, row0, k3, 0, sA[1], tid), ,
        (mma16<1, 0>(af, b0, acc)));
    PHX(, if (more) stageB8(BT, Ks, col0, k3, 0, sB[1], tid),
        if (more) { VMW(4); },
        (mma16<1, 1>(af, b1, acc)));
  }

  bf16_t* o = outb + (size_t)bz * zstride;
  const float pa = PRELU ? prelu[0] : 0.0f;
#pragma unroll
  for (int m = 0; m < 8; ++m) {
#pragma unroll
    for (int n = 0; n < 4; ++n) {
#pragma unroll
      for (int j = 0; j < 4; ++j) {
        const int row = row0 + wr * 128 + m * 16 + (g << 2) + j;
        const int col = col0 + wc * 64 + n * 16 + l15;
        float t = acc[m][n][j];
        if (PRELU) {
          t += bias[col];
          t = (t > 0.0f) ? t : pa * t;
        }
        o[(size_t)row * N + col] = (bf16_t)t;
      }
    }
  }
}

// ---------------- MLP2 split-K reduce: out += b2 + sum(partials) ----------------
__global__ __launch_bounds__(256) void reduce_mlp2(const bf16_t* __restrict__ part,
                                                   const float* __restrict__ b2,
                                                   float* __restrict__ out) {
  const int idx = (blockIdx.x * 256 + threadIdx.x) * 8;
  const int col = idx & 1023;
  float a[8];
  {
    const float4 o0 = *reinterpret_cast<const float4*>(out + idx);
    const float4 o1 = *reinterpret_cast<const float4*>(out + idx + 4);
    const float4 b0 = *reinterpret_cast<const float4*>(b2 + col);
    const float4 b1 = *reinterpret_cast<const float4*>(b2 + col + 4);
    a[0] = o0.x + b0.x; a[1] = o0.y + b0.y; a[2] = o0.z + b0.z; a[3] = o0.w + b0.w;
    a[4] = o1.x + b1.x; a[5] = o1.y + b1.y; a[6] = o1.z + b1.z; a[7] = o1.w + b1.w;
  }
#pragma unroll
  for (int s = 0; s < 4; ++s) {
    const u16x8 p = *reinterpret_cast<const u16x8*>(part + (size_t)s * 4194304 + idx);
#pragma unroll
    for (int i = 0; i < 8; ++i) a[i] += __uint_as_float((u32)p[i] << 16);
  }
  float4 r0{a[0], a[1], a[2], a[3]}, r1{a[4], a[5], a[6], a[7]};
  *reinterpret_cast<float4*>(out + idx) = r0;
  *reinterpret_cast<float4*>(out + idx + 4) = r1;
}

// ---------------- Causal flash attention ----------------
__global__ __launch_bounds__(256) void attn_kernel(const bf16_t* __restrict__ kproj,
                                                   const bf16_t* __restrict__ qproj,
                                                   const bf16_t* __restrict__ vproj,
                                                   bf16_t* __restrict__ att) {
  __shared__ __align__(16) bf16_t sK[2][64 * 64];
  __shared__ __align__(16) bf16_t sVt[2][64 * 64];
  __shared__ __align__(16) bf16_t sP[4][16 * 64];
  const int tid = threadIdx.x, lane = tid & 63, w = tid >> 6;
  const int g = lane >> 4, l15 = lane & 15;
  const int f = blockIdx.x;
  const int tb = 15 - ((f >> 3) >> 3);
  const int bh = (((f >> 3) & 7) << 3) + (f & 7);
  const size_t head = (size_t)bh * (1024 * 64);
  const int b = bh >> 4, h = bh & 15;
  const int vrow = 2 * (tid >> 3);
  const int vdb = tid & 7;
  const int t0 = tb * 64;
  const int nsb = tb + 1;

  bfx8 aq0, aq1;
  {
    const bf16_t* qrow = kproj + head + (size_t)(t0 + w * 16 + l15) * 64 + g * 8;
    aq0 = *reinterpret_cast<const bfx8*>(qrow);
    aq1 = *reinterpret_cast<const bfx8*>(qrow + 32);
  }

  {
#pragma unroll
    for (int j = 0; j < 2; ++j) {
      const int chunk = j * 256 + tid;
      const int r = chunk >> 3, c = chunk & 7;
      const int cs = c ^ (r & 7);
      GLOAD_LDS16(qproj + head + (size_t)r * 64 + cs * 8, sK[0] + chunk * 8);
    }
    const bf16_t* vp = vproj + head + (size_t)vrow * 64 + vdb * 8;
    const u16x8 v0 = *reinterpret_cast<const u16x8*>(vp);
    const u16x8 v1 = *reinterpret_cast<const u16x8*>(vp + 64);
#pragma unroll
    for (int i = 0; i < 8; ++i) {
      const int d = vdb * 8 + i;
      const int cc = ((vrow >> 3) ^ i ^ vdb) & 7;
      const u32 pk = ((u32)v1[i] << 16) | (u32)v0[i];
      *reinterpret_cast<u32*>(sVt[0] + d * 64 + cc * 8 + (vrow & 7)) = pk;
    }
  }
  __syncthreads();

  f32x4 accO[4] = {};
  float m2[4], lp[4];
#pragma unroll
  for (int j = 0; j < 4; ++j) {
    m2[j] = -1e30f;
    lp[j] = 0.0f;
  }

  for (int sb = 0; sb < nsb; ++sb) {
    const int cur = sb & 1;
    const bool pf = (sb + 1 < nsb);
    const bool diag = (sb == tb);
    u16x8 v0n, v1n;
    if (pf) {
      const int s0n = (sb + 1) * 64;
#pragma unroll
      for (int j = 0; j < 2; ++j) {
        const int chunk = j * 256 + tid;
        const int r = chunk >> 3, c = chunk & 7;
        const int cs = c ^ (r & 7);
        GLOAD_LDS16(qproj + head + (size_t)(s0n + r) * 64 + cs * 8, sK[cur ^ 1] + chunk * 8);
      }
      const bf16_t* vp = vproj + head + (size_t)(s0n + vrow) * 64 + vdb * 8;
      v0n = *reinterpret_cast<const u16x8*>(vp);
      v1n = *reinterpret_cast<const u16x8*>(vp + 64);
    }

    f32x4 accS[4] = {};
    const bf16_t* sKc = sK[cur];
#pragma unroll
    for (int kk = 0; kk < 2; ++kk) {
      const bfx8 aq = kk ? aq1 : aq0;
#pragma unroll
      for (int n = 0; n < 4; ++n) {
        const int r = n * 16 + l15;
        const int c = (kk * 4 + g) ^ (r & 7);
        const bfx8 bk = *reinterpret_cast<const bfx8*>(sKc + r * 64 + c * 8);
        accS[n] = MFMA_BF16(aq, bk, accS[n]);
      }
    }

    constexpr float SC = 0.04508056640625f;  // log2(e)/32
    const int rbase = t0 + w * 16 + (g << 2);
    const int cbase = sb * 64 + l15;
    float rmx[4];
    float dmax = -3e38f;
#pragma unroll
    for (int j = 0; j < 4; ++j) {
      const int t = rbase + j;
      float mx = -1e30f;
      if (diag) {
#pragma unroll
        for (int n = 0; n < 4; ++n) {
          float v = accS[n][j] * SC;
          v = ((cbase + n * 16) <= t) ? v : -1e30f;
          accS[n][j] = v;
          mx = fmaxf(mx, v);
        }
      } else {
#pragma unroll
        for (int n = 0; n < 4; ++n) {
          const float v = accS[n][j] * SC;
          accS[n][j] = v;
          mx = fmaxf(mx, v);
        }
      }
      rmx[j] = mx;
      dmax = fmaxf(dmax, mx - m2[j]);
    }
    if (__any(dmax > 8.0f)) {
#pragma unroll
      for (int j = 0; j < 4; ++j) {
        float mx = rmx[j];
        mx = fmaxf(mx, __shfl_xor(mx, 1));
        mx = fmaxf(mx, __shfl_xor(mx, 2));
        mx = fmaxf(mx, __shfl_xor(mx, 4));
        mx = fmaxf(mx, __shfl_xor(mx, 8));
        const float mnew = fmaxf(m2[j], mx);
        const float al = __builtin_amdgcn_exp2f(m2[j] - mnew);
        m2[j] = mnew;
        lp[j] *= al;
#pragma unroll
        for (int n = 0; n < 4; ++n) accO[n][j] *= al;
      }
    }
#pragma unroll
    for (int j = 0; j < 4; ++j) {
      float s = 0.0f;
#pragma unroll
      for (int n = 0; n < 4; ++n) {
        const float p = __builtin_amdgcn_exp2f(accS[n][j] - m2[j]);
        accS[n][j] = p;
        s += p;
      }
      lp[j] += s;
    }

    bf16_t* sPw = sP[w];
#pragma unroll
    for (int n = 0; n < 4; ++n)
#pragma unroll
      for (int j = 0; j < 4; ++j) {
        const int r = (g << 2) + j;
        const int s = n * 16 + l15;
        const int cc = (s >> 3) ^ (r & 7);
        sPw[r * 64 + cc * 8 + (s & 7)] = (bf16_t)accS[n][j];
      }

    const bf16_t* sVc = sVt[cur];
#pragma unroll
    for (int kk = 0; kk < 2; ++kk) {
      bfx8 ap;
      {
        const int r = l15;
        const int c = (kk * 4 + g) ^ (r & 7);
        ap = *reinterpret_cast<const bfx8*>(sPw + r * 64 + c * 8);
      }
#pragma unroll
      for (int n = 0; n < 4; ++n) {
        const int d = n * 16 + l15;
        const int c = (kk * 4 + g) ^ (d & 7) ^ ((d >> 3) & 7);
        const bfx8 bv = *reinterpret_cast<const bfx8*>(sVc + d * 64 + c * 8);
        accO[n] = MFMA_BF16(ap, bv, accO[n]);
      }
    }

    if (pf) {
#pragma unroll
      for (int i = 0; i < 8; ++i) {
        const int d = vdb * 8 + i;
        const int cc = ((vrow >> 3) ^ i ^ vdb) & 7;
        const u32 pk = ((u32)v1n[i] << 16) | (u32)v0n[i];
        *reinterpret_cast<u32*>(sVt[cur ^ 1] + d * 64 + cc * 8 + (vrow & 7)) = pk;
      }
    }
    __syncthreads();
  }

#pragma unroll
  for (int j = 0; j < 4; ++j) {
    float l = lp[j];
    l += __shfl_xor(l, 1);
    l += __shfl_xor(l, 2);
    l += __shfl_xor(l, 4);
    l += __shfl_xor(l, 8);
    const float inv = 1.0f / l;
    const int t = t0 + w * 16 + (g << 2) + j;
#pragma unroll
    for (int n = 0; n < 4; ++n) {
      const int d = n * 16 + l15;
      att[((size_t)(b * 1024 + t)) * 1024 + h * 64 + d] = (bf16_t)(accO[n][j] * inv);
    }
  }
}

extern "C" void kernel_launch(void* const* d_in, const int* in_sizes, int n_in,
                              void* d_out, int out_size, void* d_ws, size_t ws_size,
                              hipStream_t stream) {
  (void)in_sizes; (void)n_in; (void)out_size; (void)ws_size;
  const float* x = (const float*)d_in[0];
  const float* ln1w = (const float*)d_in[1];
  const float* ln1b = (const float*)d_in[2];
  const float* Wk = (const float*)d_in[3];
  const float* Wq = (const float*)d_in[4];
  const float* Wv = (const float*)d_in[5];
  const float* Wo = (const float*)d_in[6];
  const float* bo = (const float*)d_in[7];
  const float* ln2w = (const float*)d_in[8];
  const float* ln2b = (const float*)d_in[9];
  const float* W1 = (const float*)d_in[10];
  const float* b1 = (const float*)d_in[11];
  const float* pa = (const float*)d_in[12];
  const float* W2 = (const float*)d_in[13];
  const float* b2 = (const float*)d_in[14];
  float* out = (float*)d_out;
  char* ws = (char*)d_ws;
  const size_t MB = 1ull << 20;
  bf16_t* h1 = (bf16_t*)(ws + 0 * MB);      // [4096,1024]
  bf16_t* h2 = (bf16_t*)(ws + 8 * MB);      // [4096,1024]
  bf16_t* qb = (bf16_t*)(ws + 16 * MB);     // [B*H,1024,64]
  bf16_t* kb = (bf16_t*)(ws + 24 * MB);
  bf16_t* vb = (bf16_t*)(ws + 32 * MB);
  bf16_t* attb = (bf16_t*)(ws + 40 * MB);   // [4096,1024]
  bf16_t* fbuf = (bf16_t*)(ws + 48 * MB);   // [4096,4096]
  bf16_t* part = (bf16_t*)(ws + 16 * MB);   // MLP2 partials [4][4096,1024]
  bf16_t* WqkvT = (bf16_t*)(ws + 80 * MB);  // [3072,1024]
  bf16_t* WoT = (bf16_t*)(ws + 86 * MB);    // [1024,1024]
  bf16_t* W1T = (bf16_t*)(ws + 88 * MB);    // [4096,1024]
  bf16_t* W2T = (bf16_t*)(ws + 96 * MB);    // [1024,4096]

  transpose_qkv<<<dim3(16, 48), 256, 0, stream>>>(Wq, Wk, Wv, WqkvT);
  transpose_cast<<<dim3(16, 16), 256, 0, stream>>>(Wo, WoT, 1024, 1024);
  transpose_cast<<<dim3(16, 64), 256, 0, stream>>>(W1, W1T, 1024, 4096);
  transpose_cast<<<dim3(64, 16), 256, 0, stream>>>(W2, W2T, 4096, 1024);

  ln_kernel<<<4096, 256, 0, stream>>>(x, ln1w, ln1b, h1);
  gemm_bt<EPI_QKV, 256, 256, 512><<<dim3(16, 12), 512, 0, stream>>>(
      h1, WqkvT, nullptr, nullptr, nullptr, qb, kb, vb, 1024, 3072);
  attn_kernel<<<1024, 256, 0, stream>>>(kb, qb, vb, attb);
  gemm_bt<EPI_WO, 64, 128, 256><<<dim3(64, 8), 256, 0, stream>>>(
      attb, WoT, bo, x, out, nullptr, nullptr, nullptr, 1024, 1024);
  ln_kernel<<<4096, 256, 0, stream>>>(out, ln2w, ln2b, h2);
  gemm_8ph<true><<<256, 512, 0, stream>>>(h2, W1T, b1, pa, fbuf, 1024, 1024, 4096, 0, 16,
                                          256);
  gemm_8ph<false><<<256, 512, 0, stream>>>(fbuf, W2T, nullptr, nullptr, part, 4096, 1024,
                                           1024, 4194304, 16, 64);
  reduce_mlp2<<<2048, 256, 0, stream>>>(part, b2, out);
}